// Round 1
// baseline (224.890 us; speedup 1.0000x reference)
//
#include <hip/hip_runtime.h>
#include <math.h>

#define BB 8192
#define KK 32
#define DD 129      // hyperboloid dim = D + 1
#define VV 2048
#define NN 33       // K + 1
#define TOPK 10
#define WPB 4       // waves (= batches) per block; waves are fully autonomous (no barriers)

__device__ __forceinline__ float fast_rcp(float x) { return __builtin_amdgcn_rcpf(x); }

__global__ __launch_bounds__(256) void lr_fused(
    const float* __restrict__ anchor,
    const float* __restrict__ positive,
    const float* __restrict__ neg,
    const float* __restrict__ tree,
    const int* __restrict__ a_idx,
    const int* __restrict__ p_idx,
    const int* __restrict__ n_idx,
    float* __restrict__ partial)
{
    // all slices are per-wave private: no __syncthreads anywhere
    __shared__ float  st_[WPB][NN];     // tree distances t
    __shared__ float  sx_[WPB][NN];     // raw -inner (pre-acosh)
    __shared__ float  sd_[WPB][NN];     // d
    __shared__ float4 sitem[WPB][NN];   // {d, rel, disc, 0}

    const int t    = threadIdx.x;
    const int wave = t >> 6;
    const int lane = t & 63;
    const int g8   = lane >> 3;        // 8 row-groups per wave
    const int s8   = lane & 7;         // 8 lanes per row (float4 each -> 32 floats/step)
    const int b    = blockIdx.x * WPB + wave;

    // ---- tree gather (lanes >=33 read a clamped dup, discarded) ----
    const int ai  = a_idx[b];
    const int col = (lane == 0) ? p_idx[b]
                                : n_idx[(size_t)b * KK + ((lane < NN ? lane : KK) - 1)];
    const float tg = tree[(size_t)ai * VV + col];
    if (lane < NN) st_[wave][lane] = tg;

    const float* ab = anchor   + (size_t)b * DD;
    const float* pb = positive + (size_t)b * DD;
    const float* nb = neg      + (size_t)b * (KK * DD);

    // anchor slice for this lane's 16 columns: s8*4 + 32*k, k=0..3
    const float4 ar0 = *(const float4*)(ab +      s8 * 4);
    const float4 ar1 = *(const float4*)(ab + 32 + s8 * 4);
    const float4 ar2 = *(const float4*)(ab + 64 + s8 * 4);
    const float4 ar3 = *(const float4*)(ab + 96 + s8 * 4);
    const float a128 = ab[128];

    // ---- dots: 8 lanes/row x 8 rows/round, float4 loads fused into FMA ----
    // rows 0..32; round 4 only group 0 active (row 32), others exec-masked (no fetch)
    #pragma unroll
    for (int r = 0; r < 5; ++r) {
        const int row  = r * 8 + g8;
        const bool act = (r < 4) || (g8 == 0);
        const float* rp = (row == 0) ? pb : nb + (size_t)(row - 1) * DD;
        float s = 0.0f, f0 = 0.0f, tl = 0.0f;
        if (act) {
            const float4 c0 = *(const float4*)(rp +      s8 * 4);
            const float4 c1 = *(const float4*)(rp + 32 + s8 * 4);
            const float4 c2 = *(const float4*)(rp + 64 + s8 * 4);
            const float4 c3 = *(const float4*)(rp + 96 + s8 * 4);
            f0 = c0.x;
            if (s8 == 0) tl = rp[128];
            s = ar0.x * c0.x;
            s = fmaf(ar0.y, c0.y, s); s = fmaf(ar0.z, c0.z, s); s = fmaf(ar0.w, c0.w, s);
            s = fmaf(ar1.x, c1.x, s); s = fmaf(ar1.y, c1.y, s);
            s = fmaf(ar1.z, c1.z, s); s = fmaf(ar1.w, c1.w, s);
            s = fmaf(ar2.x, c2.x, s); s = fmaf(ar2.y, c2.y, s);
            s = fmaf(ar2.z, c2.z, s); s = fmaf(ar2.w, c2.w, s);
            s = fmaf(ar3.x, c3.x, s); s = fmaf(ar3.y, c3.y, s);
            s = fmaf(ar3.z, c3.z, s); s = fmaf(ar3.w, c3.w, s);
        }
        // reduce across the 8 column-lanes of this group (xor bits 0..2 stay in-group)
        s += __shfl_xor(s, 4, 64);
        s += __shfl_xor(s, 2, 64);
        s += __shfl_xor(s, 1, 64);
        if (act && s8 == 0) {
            const float full = fmaf(a128, tl, s);       // sum_{0..128} a*v
            // -inner = 2*u0*v0 - full   (u0 = ar0.x, v0 = f0 for s8==0)
            sx_[wave][row] = fmaxf(fmaf(2.0f * ar0.x, f0, -full), 1.0f + 1e-07f);
        }
    }

    // ---- dense acosh pass (one shot, 33/64 lanes) ----
    float dlane = 0.0f;
    if (lane < NN) {
        float x = sx_[wave][lane];
        dlane = __logf(x + sqrtf(x * x - 1.0f));      // acosh(x)
        sd_[wave][lane] = dlane;
    }

    // ---- rel + stable rank -> disc (broadcast LDS reads, uniform j) ----
    if (lane < NN) {
        float maxt = st_[wave][0];
        #pragma unroll
        for (int j = 1; j < NN; ++j) maxt = fmaxf(maxt, st_[wave][j]);
        float rel = (maxt - tg + 1e-06f) * fast_rcp(maxt + 1e-06f);

        int cnt = 0;
        #pragma unroll
        for (int j = 0; j < NN; ++j) {
            float dj = sd_[wave][j];
            cnt += (int)((dj < dlane) | ((dj == dlane) & (j < lane)));
        }
        float disc = (cnt + 1 <= TOPK) ? fast_rcp(log2f((float)(cnt + 2))) : 0.0f;
        sitem[wave][lane] = make_float4(dlane, rel, disc, 0.0f);
    }

    // ---- IDCG: stable descending position, butterfly sum -> inv in regs ----
    float c = 0.0f;
    if (lane < NN) {
        float ri = sitem[wave][lane].y;
        int pos = 0;
        #pragma unroll
        for (int j = 0; j < NN; ++j) {
            float rj = sitem[wave][j].y;               // uniform j: broadcast
            pos += (int)((rj > ri) | ((rj == ri) & (j < lane)));
        }
        if (pos < TOPK) c = ri * fast_rcp(log2f((float)(pos + 2)));
    }
    #pragma unroll
    for (int off = 32; off > 0; off >>= 1) c += __shfl_xor(c, off, 64);
    const float inv = (c > 0.0f) ? fast_rcp(c) : 0.0f;

    // ---- pair sum over i<j only (term is symmetric: full sum = 2*this) ----
    // 528 pairs; p = j*(j-1)/2 + i. Exact fp32 triangular decode.
    float acc = 0.0f;
    #pragma unroll
    for (int it = 0; it < 9; ++it) {
        int p = it * 64 + lane;                  // 0..575
        float vmask = (p < 528) ? 1.0f : 0.0f;
        int pc = (p < 528) ? p : 527;
        int j = (int)((1.0f + sqrtf((float)(8 * pc + 1))) * 0.5f);
        int tj = (j * (j - 1)) >> 1;
        if (tj > pc) { --j; tj = (j * (j - 1)) >> 1; }   // safety guard
        int i = pc - tj;
        float4 Ii = sitem[wave][i];
        float4 Ij = sitem[wave][j];
        float dd    = Ij.x - Ii.x;               // d[j] - d[i]
        float drel  = Ii.y - Ij.y;
        float ddisc = Ii.z - Ij.z;
        float t1  = drel * fabsf(ddisc) * (inv * vmask);   // S * delta (masked)
        float e   = __expf(-dd);
        float num = (drel >= 0.0f) ? 1.0f : e;
        acc = fmaf(t1 * num * fast_rcp(1.0f + e), -dd, acc);
    }
    #pragma unroll
    for (int off = 32; off > 0; off >>= 1) acc += __shfl_xor(acc, off, 64);
    // 0.5 * full-sum = sum over i<j = acc
    if (lane == 0) partial[b] = acc;
}

__global__ __launch_bounds__(256) void lr_reduce(
    const float* __restrict__ partial, float* __restrict__ out)
{
    __shared__ float swave[4];
    const float4* p4 = (const float4*)partial;
    float acc = 0.0f;
    #pragma unroll
    for (int c = 0; c < (BB / 4) / 256; ++c) {
        float4 v = p4[c * 256 + threadIdx.x];
        acc += (v.x + v.y) + (v.z + v.w);
    }
    #pragma unroll
    for (int off = 32; off > 0; off >>= 1) acc += __shfl_xor(acc, off, 64);
    if ((threadIdx.x & 63) == 0) swave[threadIdx.x >> 6] = acc;
    __syncthreads();
    if (threadIdx.x == 0)
        out[0] = (swave[0] + swave[1] + swave[2] + swave[3]) * (0.15f / (float)BB);
}

extern "C" void kernel_launch(void* const* d_in, const int* in_sizes, int n_in,
                              void* d_out, int out_size, void* d_ws, size_t ws_size,
                              hipStream_t stream)
{
    const float* anchor   = (const float*)d_in[0];
    const float* positive = (const float*)d_in[1];
    const float* neg      = (const float*)d_in[2];
    const float* tree     = (const float*)d_in[3];
    const int*   a_idx    = (const int*)d_in[4];
    const int*   p_idx    = (const int*)d_in[5];
    const int*   n_idx    = (const int*)d_in[6];
    float* partial = (float*)d_ws;   // BB floats = 32 KB scratch

    lr_fused<<<BB / WPB, 256, 0, stream>>>(anchor, positive, neg, tree,
                                           a_idx, p_idx, n_idx, partial);
    lr_reduce<<<1, 256, 0, stream>>>(partial, (float*)d_out);
}